// Round 1
// baseline (345.331 us; speedup 1.0000x reference)
//
#include <hip/hip_runtime.h>
#include <math.h>

#define BB 16
#define NN 4096
#define EE 65536
#define IN_F 128
#define HH 512
#define F1 64
#define D1 512
#define D2 32768
#define EPSV 1e-5f

// ---------------- GCN support: histogram / scan / CSR fill ----------------

__global__ void k_hist(const int* __restrict__ dst, int* __restrict__ cnt) {
    int i = blockIdx.x * 256 + threadIdx.x;
    if (i < EE) atomicAdd(&cnt[dst[i]], 1);
}

__global__ void k_scan(const int* __restrict__ cnt, int* __restrict__ row_start,
                       int* __restrict__ cursor, float* __restrict__ dis) {
    __shared__ int lds[1024];
    int tid = threadIdx.x;
    int v0 = cnt[tid * 4 + 0];
    int v1 = cnt[tid * 4 + 1];
    int v2 = cnt[tid * 4 + 2];
    int v3 = cnt[tid * 4 + 3];
    int s = v0 + v1 + v2 + v3;
    lds[tid] = s;
    __syncthreads();
    for (int off = 1; off < 1024; off <<= 1) {
        int t = (tid >= off) ? lds[tid - off] : 0;
        __syncthreads();
        lds[tid] += t;
        __syncthreads();
    }
    int e = (tid > 0) ? lds[tid - 1] : 0;
    int idx = tid * 4;
    row_start[idx + 0] = e; cursor[idx + 0] = e; dis[idx + 0] = rsqrtf((float)(v0 + 1)); e += v0;
    row_start[idx + 1] = e; cursor[idx + 1] = e; dis[idx + 1] = rsqrtf((float)(v1 + 1)); e += v1;
    row_start[idx + 2] = e; cursor[idx + 2] = e; dis[idx + 2] = rsqrtf((float)(v2 + 1)); e += v2;
    row_start[idx + 3] = e; cursor[idx + 3] = e; dis[idx + 3] = rsqrtf((float)(v3 + 1)); e += v3;
    if (tid == 1023) row_start[4096] = lds[1023];
}

__global__ void k_fill(const int* __restrict__ src, const int* __restrict__ dst,
                       int* __restrict__ cursor, int* __restrict__ csr_src) {
    int i = blockIdx.x * 256 + threadIdx.x;
    if (i < EE) {
        int d = dst[i];
        int p = atomicAdd(&cursor[d], 1);
        csr_src[p] = src[i];
    }
}

// ---------------- GCN layer 0 input transform: hws0 = dis[n] * (pos @ W0) ----------------
// layout: hws0[n][b][g], node-major 4KB blocks

__global__ void k_hw0(const float* __restrict__ pos, const float* __restrict__ W0,
                      const float* __restrict__ dis, float* __restrict__ hws0) {
    int n = blockIdx.x;
    int g = threadIdx.x & 63;
    int b0 = threadIdx.x >> 6;  // 0..3
    float d = dis[n];
    float w0 = W0[g], w1 = W0[64 + g], w2 = W0[128 + g];
#pragma unroll
    for (int bb = 0; bb < 4; ++bb) {
        int b = b0 + 4 * bb;
        const float* p = pos + b * (NN * 3) + n * 3;
        hws0[n * 1024 + b * 64 + g] = d * (p[0] * w0 + p[1] * w1 + p[2] * w2);
    }
}

// ---------------- GCN layer 0 aggregate + layer-1 matmul fused ----------------
// h0[b][g] = dis[n]*(hws0[n] + sum_in hws0[src]) + b0[g]
// hws1[n][b][g] = dis[n] * (h0 @ W1)

__global__ void k_layer0(const float* __restrict__ hws0, const int* __restrict__ row_start,
                         const int* __restrict__ csr_src, const float* __restrict__ dis,
                         const float* __restrict__ bias0, const float* __restrict__ W1,
                         float* __restrict__ hws1) {
    __shared__ float h0[16][64];
    int n = blockIdx.x;
    int g = threadIdx.x & 63;
    int b0 = threadIdx.x >> 6;
    int rs = row_start[n], re = row_start[n + 1];
    float acc[4];
#pragma unroll
    for (int bb = 0; bb < 4; ++bb) acc[bb] = hws0[n * 1024 + (b0 + 4 * bb) * 64 + g];
    for (int e = rs; e < re; ++e) {
        int s = csr_src[e];
        const float* p = hws0 + s * 1024 + b0 * 64 + g;
#pragma unroll
        for (int bb = 0; bb < 4; ++bb) acc[bb] += p[bb * 256];
    }
    float d = dis[n];
    float bg = bias0[g];
#pragma unroll
    for (int bb = 0; bb < 4; ++bb) h0[b0 + 4 * bb][g] = acc[bb] * d + bg;
    __syncthreads();
    float o[4] = {0.f, 0.f, 0.f, 0.f};
    for (int f = 0; f < 64; ++f) {
        float w = W1[f * 64 + g];
#pragma unroll
        for (int bb = 0; bb < 4; ++bb) o[bb] += h0[b0 + 4 * bb][f] * w;
    }
#pragma unroll
    for (int bb = 0; bb < 4; ++bb) hws1[n * 1024 + (b0 + 4 * bb) * 64 + g] = o[bb] * d;
}

// ---------------- GCN layer 1 aggregate: h1 = dis[n]*(hws1[n]+sum) + b1 ----------------

__global__ void k_agg1(const float* __restrict__ hws1, const int* __restrict__ row_start,
                       const int* __restrict__ csr_src, const float* __restrict__ dis,
                       const float* __restrict__ bias1, float* __restrict__ h1) {
    int n = blockIdx.x;
    int g = threadIdx.x & 63;
    int b0 = threadIdx.x >> 6;
    int rs = row_start[n], re = row_start[n + 1];
    float acc[4];
#pragma unroll
    for (int bb = 0; bb < 4; ++bb) acc[bb] = hws1[n * 1024 + (b0 + 4 * bb) * 64 + g];
    for (int e = rs; e < re; ++e) {
        int s = csr_src[e];
        const float* p = hws1 + s * 1024 + b0 * 64 + g;
#pragma unroll
        for (int bb = 0; bb < 4; ++bb) acc[bb] += p[bb * 256];
    }
    float d = dis[n];
    float bg = bias1[g];
#pragma unroll
    for (int bb = 0; bb < 4; ++bb) h1[n * 1024 + (b0 + 4 * bb) * 64 + g] = acc[bb] * d + bg;
}

// ---------------- GRUCell ----------------
// thread t: b = t&15, j = t>>4 (0..511); computes all three gates for (b,j)

__global__ void k_gru(const float* __restrict__ x, const float* __restrict__ hidden,
                      const float* __restrict__ w_ih, const float* __restrict__ b_ih,
                      const float* __restrict__ w_hh, const float* __restrict__ b_hh,
                      float* __restrict__ nh_out, float* __restrict__ nh_ws) {
    int t = blockIdx.x * 256 + threadIdx.x;
    int b = t & 15;
    int j = t >> 4;
    float air = b_ih[j], aiz = b_ih[HH + j], ain = b_ih[2 * HH + j];
    const float4* xr = (const float4*)(x + b * IN_F);
    const float4* wi0 = (const float4*)(w_ih + (size_t)j * IN_F);
    const float4* wi1 = (const float4*)(w_ih + (size_t)(HH + j) * IN_F);
    const float4* wi2 = (const float4*)(w_ih + (size_t)(2 * HH + j) * IN_F);
    for (int k = 0; k < IN_F / 4; ++k) {
        float4 xv = xr[k];
        float4 a = wi0[k], c = wi1[k], d = wi2[k];
        air += xv.x * a.x + xv.y * a.y + xv.z * a.z + xv.w * a.w;
        aiz += xv.x * c.x + xv.y * c.y + xv.z * c.z + xv.w * c.w;
        ain += xv.x * d.x + xv.y * d.y + xv.z * d.z + xv.w * d.w;
    }
    float ahr = b_hh[j], ahz = b_hh[HH + j], ahn = b_hh[2 * HH + j];
    const float4* hr = (const float4*)(hidden + b * HH);
    const float4* wh0 = (const float4*)(w_hh + (size_t)j * HH);
    const float4* wh1 = (const float4*)(w_hh + (size_t)(HH + j) * HH);
    const float4* wh2 = (const float4*)(w_hh + (size_t)(2 * HH + j) * HH);
    for (int k = 0; k < HH / 4; ++k) {
        float4 hv = hr[k];
        float4 a = wh0[k], c = wh1[k], d = wh2[k];
        ahr += hv.x * a.x + hv.y * a.y + hv.z * a.z + hv.w * a.w;
        ahz += hv.x * c.x + hv.y * c.y + hv.z * c.z + hv.w * c.w;
        ahn += hv.x * d.x + hv.y * d.y + hv.z * d.z + hv.w * d.w;
    }
    float r = 1.f / (1.f + expf(-(air + ahr)));
    float z = 1.f / (1.f + expf(-(aiz + ahz)));
    float nn = tanhf(ain + r * ahn);
    float hprev = hidden[b * HH + j];
    float nh = (1.f - z) * nn + z * hprev;
    nh_out[b * HH + j] = nh;
    nh_ws[b * HH + j] = nh;
}

// ---------------- MLP layer 1: H->D1, Linear+PReLU+BN ----------------
// 2 blocks x 256; thread owns column j, accumulates all 16 batches

__global__ void k_mlp1(const float* __restrict__ nh, const float* __restrict__ w1,
                       const float* __restrict__ b1, const float* __restrict__ alpha1,
                       const float* __restrict__ g1, const float* __restrict__ bt1,
                       const float* __restrict__ mu1, const float* __restrict__ var1,
                       float* __restrict__ m1) {
    __shared__ float s_nh[16 * 512];
    int tid = threadIdx.x;
    for (int i = tid; i < (16 * 512) / 4; i += 256)
        ((float4*)s_nh)[i] = ((const float4*)nh)[i];
    __syncthreads();
    int j = blockIdx.x * 256 + tid;
    float acc[16];
#pragma unroll
    for (int b = 0; b < 16; ++b) acc[b] = 0.f;
    for (int k = 0; k < 512; ++k) {
        float w = w1[k * D1 + j];
#pragma unroll
        for (int b = 0; b < 16; ++b) acc[b] += s_nh[b * 512 + k] * w;
    }
    float bj = b1[j], al = alpha1[j], ga = g1[j], be = bt1[j], mu = mu1[j];
    float iv = rsqrtf(var1[j] + EPSV);
#pragma unroll
    for (int b = 0; b < 16; ++b) {
        float v = acc[b] + bj;
        v = v > 0.f ? v : al * v;
        m1[b * D1 + j] = ga * (v - mu) * iv + be;
    }
}

// ---------------- MLP layer 2: D1->D2, Linear+PReLU+BN ----------------
// 64 blocks x 256; thread owns columns j0, j0+256; 16 batches each

__global__ void k_mlp2(const float* __restrict__ m1, const float* __restrict__ w2,
                       const float* __restrict__ b2, const float* __restrict__ alpha2,
                       const float* __restrict__ g2, const float* __restrict__ bt2,
                       const float* __restrict__ mu2, const float* __restrict__ var2,
                       float* __restrict__ m2) {
    __shared__ float s_m1[16 * 512];
    int tid = threadIdx.x;
    for (int i = tid; i < (16 * 512) / 4; i += 256)
        ((float4*)s_m1)[i] = ((const float4*)m1)[i];
    __syncthreads();
    int j0 = blockIdx.x * 512 + tid;
    int j1 = j0 + 256;
    float acc0[16], acc1[16];
#pragma unroll
    for (int b = 0; b < 16; ++b) { acc0[b] = 0.f; acc1[b] = 0.f; }
    for (int k = 0; k < 512; ++k) {
        float wa = w2[(size_t)k * D2 + j0];
        float wb = w2[(size_t)k * D2 + j1];
#pragma unroll
        for (int b = 0; b < 16; ++b) {
            float mv = s_m1[b * 512 + k];
            acc0[b] += mv * wa;
            acc1[b] += mv * wb;
        }
    }
    {
        float bj = b2[j0], al = alpha2[j0], ga = g2[j0], be = bt2[j0], mu = mu2[j0];
        float iv = rsqrtf(var2[j0] + EPSV);
#pragma unroll
        for (int b = 0; b < 16; ++b) {
            float v = acc0[b] + bj;
            v = v > 0.f ? v : al * v;
            m2[(size_t)b * D2 + j0] = ga * (v - mu) * iv + be;
        }
    }
    {
        float bj = b2[j1], al = alpha2[j1], ga = g2[j1], be = bt2[j1], mu = mu2[j1];
        float iv = rsqrtf(var2[j1] + EPSV);
#pragma unroll
        for (int b = 0; b < 16; ++b) {
            float v = acc1[b] + bj;
            v = v > 0.f ? v : al * v;
            m2[(size_t)b * D2 + j1] = ga * (v - mu) * iv + be;
        }
    }
}

// ---------------- Output head: y[b][n][c] = [gru_out | h1] @ w_out + b_out ----------------

__global__ void k_out(const float* __restrict__ m2, const float* __restrict__ h1,
                      const float* __restrict__ w_out, const float* __restrict__ b_out,
                      float* __restrict__ y) {
    __shared__ float sw[216];
    __shared__ float sb[3];
    int tid = threadIdx.x;
    if (tid < 216) sw[tid] = w_out[tid];
    if (tid < 3) sb[tid] = b_out[tid];
    __syncthreads();
    int t = blockIdx.x * 256 + tid;
    int n = t & (NN - 1);
    int b = t >> 12;
    float y0 = sb[0], y1 = sb[1], y2 = sb[2];
    const float4* gp = (const float4*)(m2 + (size_t)b * D2 + n * 8);
    float4 ga = gp[0], gb = gp[1];
    float gg[8] = {ga.x, ga.y, ga.z, ga.w, gb.x, gb.y, gb.z, gb.w};
#pragma unroll
    for (int g = 0; g < 8; ++g) {
        y0 += gg[g] * sw[g * 3 + 0];
        y1 += gg[g] * sw[g * 3 + 1];
        y2 += gg[g] * sw[g * 3 + 2];
    }
    const float* hp = h1 + n * 1024 + b * 64;
#pragma unroll
    for (int f = 0; f < 64; f += 4) {
        float4 hv = *(const float4*)(hp + f);
        y0 += hv.x * sw[(8 + f) * 3 + 0] + hv.y * sw[(9 + f) * 3 + 0] +
              hv.z * sw[(10 + f) * 3 + 0] + hv.w * sw[(11 + f) * 3 + 0];
        y1 += hv.x * sw[(8 + f) * 3 + 1] + hv.y * sw[(9 + f) * 3 + 1] +
              hv.z * sw[(10 + f) * 3 + 1] + hv.w * sw[(11 + f) * 3 + 1];
        y2 += hv.x * sw[(8 + f) * 3 + 2] + hv.y * sw[(9 + f) * 3 + 2] +
              hv.z * sw[(10 + f) * 3 + 2] + hv.w * sw[(11 + f) * 3 + 2];
    }
    float* yo = y + (size_t)b * (NN * 3) + n * 3;
    yo[0] = y0;
    yo[1] = y1;
    yo[2] = y2;
}

// ---------------- launcher ----------------

extern "C" void kernel_launch(void* const* d_in, const int* in_sizes, int n_in,
                              void* d_out, int out_size, void* d_ws, size_t ws_size,
                              hipStream_t stream) {
    const float* x      = (const float*)d_in[0];
    const float* pos    = (const float*)d_in[1];
    const float* hidden = (const float*)d_in[2];
    const int*   ei     = (const int*)d_in[3];
    const float* W0     = (const float*)d_in[4];
    const float* b0     = (const float*)d_in[5];
    const float* W1     = (const float*)d_in[6];
    const float* b1     = (const float*)d_in[7];
    const float* w_ih   = (const float*)d_in[8];
    const float* b_ih   = (const float*)d_in[9];
    const float* w_hh   = (const float*)d_in[10];
    const float* b_hh   = (const float*)d_in[11];
    const float* mlp_w1 = (const float*)d_in[12];
    const float* mlp_b1 = (const float*)d_in[13];
    const float* alpha1 = (const float*)d_in[14];
    const float* bn1g   = (const float*)d_in[15];
    const float* bn1b   = (const float*)d_in[16];
    const float* bn1m   = (const float*)d_in[17];
    const float* bn1v   = (const float*)d_in[18];
    const float* mlp_w2 = (const float*)d_in[19];
    const float* mlp_b2 = (const float*)d_in[20];
    const float* alpha2 = (const float*)d_in[21];
    const float* bn2g   = (const float*)d_in[22];
    const float* bn2b   = (const float*)d_in[23];
    const float* bn2m   = (const float*)d_in[24];
    const float* bn2v   = (const float*)d_in[25];
    const float* w_out  = (const float*)d_in[26];
    const float* b_out  = (const float*)d_in[27];

    float* out = (float*)d_out;
    float* ws = (float*)d_ws;

    // workspace layout (float offsets)
    float* bufA = ws;                 // 4096*1024: hws0, later reused as h1
    float* bufB = ws + 4194304;       // 4096*1024: hws1
    float* m2   = ws + 8388608;       // 16*32768
    float* nh   = ws + 8912896;       // 16*512
    float* m1s  = ws + 8921088;       // 16*512
    float* dis  = ws + 8929280;       // 4096
    int* wsi       = (int*)(ws + 8933376);
    int* cnt       = wsi;                       // 4096
    int* row_start = wsi + 4096;                // 4097
    int* cursor    = wsi + 4096 + 4097;         // 4096
    int* csr       = wsi + 4096 + 4097 + 4096;  // 65536

    const int* srcp = ei;
    const int* dstp = ei + EE;

    hipMemsetAsync(cnt, 0, 4096 * sizeof(int), stream);
    k_hist<<<EE / 256, 256, 0, stream>>>(dstp, cnt);
    k_scan<<<1, 1024, 0, stream>>>(cnt, row_start, cursor, dis);
    k_fill<<<EE / 256, 256, 0, stream>>>(srcp, dstp, cursor, csr);
    k_hw0<<<NN, 256, 0, stream>>>(pos, W0, dis, bufA);
    k_layer0<<<NN, 256, 0, stream>>>(bufA, row_start, csr, dis, b0, W1, bufB);
    k_agg1<<<NN, 256, 0, stream>>>(bufB, row_start, csr, dis, b1, bufA);
    k_gru<<<32, 256, 0, stream>>>(x, hidden, w_ih, b_ih, w_hh, b_hh, out + BB * NN * 3, nh);
    k_mlp1<<<2, 256, 0, stream>>>(nh, mlp_w1, mlp_b1, alpha1, bn1g, bn1b, bn1m, bn1v, m1s);
    k_mlp2<<<64, 256, 0, stream>>>(m1s, mlp_w2, mlp_b2, alpha2, bn2g, bn2b, bn2m, bn2v, m2);
    k_out<<<(BB * NN) / 256, 256, 0, stream>>>(m2, bufA, w_out, b_out, out);
}

// Round 2
// 177.558 us; speedup vs baseline: 1.9449x; 1.9449x over previous
//
#include <hip/hip_runtime.h>
#include <math.h>

#define BB 16
#define NN 4096
#define EE 65536
#define IN_F 128
#define HH 512
#define F1 64
#define D1 512
#define D2 32768
#define EPSV 1e-5f

// ---------------- GCN support: histogram / scan / CSR fill ----------------

__global__ void k_hist(const int* __restrict__ dst, int* __restrict__ cnt) {
    int i = blockIdx.x * 256 + threadIdx.x;
    if (i < EE) atomicAdd(&cnt[dst[i]], 1);
}

__global__ void k_scan(const int* __restrict__ cnt, int* __restrict__ row_start,
                       int* __restrict__ cursor, float* __restrict__ dis) {
    __shared__ int lds[1024];
    int tid = threadIdx.x;
    int v0 = cnt[tid * 4 + 0];
    int v1 = cnt[tid * 4 + 1];
    int v2 = cnt[tid * 4 + 2];
    int v3 = cnt[tid * 4 + 3];
    int s = v0 + v1 + v2 + v3;
    lds[tid] = s;
    __syncthreads();
    for (int off = 1; off < 1024; off <<= 1) {
        int t = (tid >= off) ? lds[tid - off] : 0;
        __syncthreads();
        lds[tid] += t;
        __syncthreads();
    }
    int e = (tid > 0) ? lds[tid - 1] : 0;
    int idx = tid * 4;
    row_start[idx + 0] = e; cursor[idx + 0] = e; dis[idx + 0] = rsqrtf((float)(v0 + 1)); e += v0;
    row_start[idx + 1] = e; cursor[idx + 1] = e; dis[idx + 1] = rsqrtf((float)(v1 + 1)); e += v1;
    row_start[idx + 2] = e; cursor[idx + 2] = e; dis[idx + 2] = rsqrtf((float)(v2 + 1)); e += v2;
    row_start[idx + 3] = e; cursor[idx + 3] = e; dis[idx + 3] = rsqrtf((float)(v3 + 1)); e += v3;
    if (tid == 1023) row_start[4096] = lds[1023];
}

__global__ void k_fill(const int* __restrict__ src, const int* __restrict__ dst,
                       int* __restrict__ cursor, int* __restrict__ csr_src) {
    int i = blockIdx.x * 256 + threadIdx.x;
    if (i < EE) {
        int d = dst[i];
        int p = atomicAdd(&cursor[d], 1);
        csr_src[p] = src[i];
    }
}

// ---------------- GCN layer 0 input transform: hws0 = dis[n] * (pos @ W0) ----------------

__global__ void k_hw0(const float* __restrict__ pos, const float* __restrict__ W0,
                      const float* __restrict__ dis, float* __restrict__ hws0) {
    int n = blockIdx.x;
    int g = threadIdx.x & 63;
    int b0 = threadIdx.x >> 6;  // 0..3
    float d = dis[n];
    float w0 = W0[g], w1 = W0[64 + g], w2 = W0[128 + g];
#pragma unroll
    for (int bb = 0; bb < 4; ++bb) {
        int b = b0 + 4 * bb;
        const float* p = pos + b * (NN * 3) + n * 3;
        hws0[n * 1024 + b * 64 + g] = d * (p[0] * w0 + p[1] * w1 + p[2] * w2);
    }
}

// ---------------- GCN layer 0 aggregate + layer-1 matmul fused ----------------

__global__ void k_layer0(const float* __restrict__ hws0, const int* __restrict__ row_start,
                         const int* __restrict__ csr_src, const float* __restrict__ dis,
                         const float* __restrict__ bias0, const float* __restrict__ W1,
                         float* __restrict__ hws1) {
    __shared__ float h0[16][64];
    int n = blockIdx.x;
    int g = threadIdx.x & 63;
    int b0 = threadIdx.x >> 6;
    int rs = row_start[n], re = row_start[n + 1];
    float acc[4];
#pragma unroll
    for (int bb = 0; bb < 4; ++bb) acc[bb] = hws0[n * 1024 + (b0 + 4 * bb) * 64 + g];
    for (int e = rs; e < re; ++e) {
        int s = csr_src[e];
        const float* p = hws0 + s * 1024 + b0 * 64 + g;
#pragma unroll
        for (int bb = 0; bb < 4; ++bb) acc[bb] += p[bb * 256];
    }
    float d = dis[n];
    float bg = bias0[g];
#pragma unroll
    for (int bb = 0; bb < 4; ++bb) h0[b0 + 4 * bb][g] = acc[bb] * d + bg;
    __syncthreads();
    float o[4] = {0.f, 0.f, 0.f, 0.f};
    for (int f = 0; f < 64; ++f) {
        float w = W1[f * 64 + g];
#pragma unroll
        for (int bb = 0; bb < 4; ++bb) o[bb] += h0[b0 + 4 * bb][f] * w;
    }
#pragma unroll
    for (int bb = 0; bb < 4; ++bb) hws1[n * 1024 + (b0 + 4 * bb) * 64 + g] = o[bb] * d;
}

// ---------------- GCN layer 1 aggregate ----------------

__global__ void k_agg1(const float* __restrict__ hws1, const int* __restrict__ row_start,
                       const int* __restrict__ csr_src, const float* __restrict__ dis,
                       const float* __restrict__ bias1, float* __restrict__ h1) {
    int n = blockIdx.x;
    int g = threadIdx.x & 63;
    int b0 = threadIdx.x >> 6;
    int rs = row_start[n], re = row_start[n + 1];
    float acc[4];
#pragma unroll
    for (int bb = 0; bb < 4; ++bb) acc[bb] = hws1[n * 1024 + (b0 + 4 * bb) * 64 + g];
    for (int e = rs; e < re; ++e) {
        int s = csr_src[e];
        const float* p = hws1 + s * 1024 + b0 * 64 + g;
#pragma unroll
        for (int bb = 0; bb < 4; ++bb) acc[bb] += p[bb * 256];
    }
    float d = dis[n];
    float bg = bias1[g];
#pragma unroll
    for (int bb = 0; bb < 4; ++bb) h1[n * 1024 + (b0 + 4 * bb) * 64 + g] = acc[bb] * d + bg;
}

// ---------------- GRUCell: 128 blocks = 16 b x 8 jblk; thread = (jloc, ks) ----------------

__global__ void k_gru(const float* __restrict__ x, const float* __restrict__ hidden,
                      const float* __restrict__ w_ih, const float* __restrict__ b_ih,
                      const float* __restrict__ w_hh, const float* __restrict__ b_hh,
                      float* __restrict__ nh_out, float* __restrict__ nh_ws) {
    __shared__ float s_x[128];
    __shared__ float s_h[512];
    __shared__ float s_p[4 * 64 * 7];
    int tid = threadIdx.x;
    int b = blockIdx.x >> 3;
    int jblk = blockIdx.x & 7;
    if (tid < 128) s_x[tid] = x[b * IN_F + tid];
    for (int i = tid; i < 512; i += 256) s_h[i] = hidden[b * HH + i];
    __syncthreads();
    int jloc = tid & 63;
    int ks = tid >> 6;  // 0..3
    int j = jblk * 64 + jloc;
    float air = 0.f, aiz = 0.f, ain = 0.f, ahr = 0.f, ahz = 0.f, ahn = 0.f;
    {
        const float4* wi0 = (const float4*)(w_ih + (size_t)j * IN_F + ks * 32);
        const float4* wi1 = (const float4*)(w_ih + (size_t)(HH + j) * IN_F + ks * 32);
        const float4* wi2 = (const float4*)(w_ih + (size_t)(2 * HH + j) * IN_F + ks * 32);
        const float4* xs = (const float4*)(s_x + ks * 32);
#pragma unroll
        for (int i = 0; i < 8; ++i) {
            float4 xv = xs[i];
            float4 a = wi0[i], c = wi1[i], d = wi2[i];
            air += xv.x * a.x + xv.y * a.y + xv.z * a.z + xv.w * a.w;
            aiz += xv.x * c.x + xv.y * c.y + xv.z * c.z + xv.w * c.w;
            ain += xv.x * d.x + xv.y * d.y + xv.z * d.z + xv.w * d.w;
        }
    }
    {
        const float4* wh0 = (const float4*)(w_hh + (size_t)j * HH + ks * 128);
        const float4* wh1 = (const float4*)(w_hh + (size_t)(HH + j) * HH + ks * 128);
        const float4* wh2 = (const float4*)(w_hh + (size_t)(2 * HH + j) * HH + ks * 128);
        const float4* hs = (const float4*)(s_h + ks * 128);
#pragma unroll 8
        for (int i = 0; i < 32; ++i) {
            float4 hv = hs[i];
            float4 a = wh0[i], c = wh1[i], d = wh2[i];
            ahr += hv.x * a.x + hv.y * a.y + hv.z * a.z + hv.w * a.w;
            ahz += hv.x * c.x + hv.y * c.y + hv.z * c.z + hv.w * c.w;
            ahn += hv.x * d.x + hv.y * d.y + hv.z * d.z + hv.w * d.w;
        }
    }
    float* pp = s_p + (ks * 64 + jloc) * 7;
    pp[0] = air; pp[1] = aiz; pp[2] = ain; pp[3] = ahr; pp[4] = ahz; pp[5] = ahn;
    __syncthreads();
    if (tid < 64) {
        int jj = jblk * 64 + tid;
        float v0 = 0.f, v1 = 0.f, v2 = 0.f, v3 = 0.f, v4 = 0.f, v5 = 0.f;
#pragma unroll
        for (int s = 0; s < 4; ++s) {
            const float* q = s_p + (s * 64 + tid) * 7;
            v0 += q[0]; v1 += q[1]; v2 += q[2]; v3 += q[3]; v4 += q[4]; v5 += q[5];
        }
        float ir = v0 + b_ih[jj], iz = v1 + b_ih[HH + jj], inn = v2 + b_ih[2 * HH + jj];
        float hr = v3 + b_hh[jj], hz = v4 + b_hh[HH + jj], hn = v5 + b_hh[2 * HH + jj];
        float r = 1.f / (1.f + expf(-(ir + hr)));
        float z = 1.f / (1.f + expf(-(iz + hz)));
        float nn = tanhf(inn + r * hn);
        float hprev = s_h[jj];
        float nh = (1.f - z) * nn + z * hprev;
        nh_out[b * HH + jj] = nh;
        nh_ws[b * HH + jj] = nh;
    }
}

// ---------------- MLP layer 1: 128 blocks = 16 b x 8 jblk; thread = (jloc, ks) ----------------

__global__ void k_mlp1(const float* __restrict__ nh, const float* __restrict__ w1,
                       const float* __restrict__ b1, const float* __restrict__ alpha1,
                       const float* __restrict__ g1, const float* __restrict__ bt1,
                       const float* __restrict__ mu1, const float* __restrict__ var1,
                       float* __restrict__ m1) {
    __shared__ float s_nh[512];
    __shared__ float s_p[4 * 64];
    int tid = threadIdx.x;
    int b = blockIdx.x >> 3;
    int jblk = blockIdx.x & 7;
    for (int i = tid; i < 512; i += 256) s_nh[i] = nh[b * HH + i];
    __syncthreads();
    int jloc = tid & 63;
    int ks = tid >> 6;
    int j = jblk * 64 + jloc;
    const float* wp = w1 + (size_t)(ks * 128) * D1 + j;
    float acc = 0.f;
#pragma unroll 4
    for (int k0 = 0; k0 < 128; k0 += 4) {
        float w0 = wp[0], w1v = wp[D1], w2v = wp[2 * D1], w3v = wp[3 * D1];
        float4 mv = *(const float4*)&s_nh[ks * 128 + k0];
        acc += mv.x * w0 + mv.y * w1v + mv.z * w2v + mv.w * w3v;
        wp += 4 * D1;
    }
    s_p[ks * 64 + jloc] = acc;
    __syncthreads();
    if (tid < 64) {
        int jj = jblk * 64 + tid;
        float v = s_p[tid] + s_p[64 + tid] + s_p[128 + tid] + s_p[192 + tid];
        v += b1[jj];
        float al = alpha1[jj];
        v = v > 0.f ? v : al * v;
        float iv = rsqrtf(var1[jj] + EPSV);
        m1[b * D1 + jj] = g1[jj] * (v - mu1[jj]) * iv + bt1[jj];
    }
}

// ---------------- MLP layer 2: 512 blocks x 256; block = 64 cols x 4 k-slices ----------------

__global__ void k_mlp2(const float* __restrict__ m1, const float* __restrict__ w2,
                       const float* __restrict__ b2, const float* __restrict__ alpha2,
                       const float* __restrict__ g2, const float* __restrict__ bt2,
                       const float* __restrict__ mu2, const float* __restrict__ var2,
                       float* __restrict__ m2) {
    __shared__ float s_m1[16 * 512];
    __shared__ float s_part[4 * 64 * 17];
    int tid = threadIdx.x;
    for (int i = tid; i < (16 * 512) / 4; i += 256)
        ((float4*)s_m1)[i] = ((const float4*)m1)[i];
    __syncthreads();
    int jloc = tid & 63;
    int ks = tid >> 6;  // 0..3, k range [ks*128, ks*128+128)
    int j = blockIdx.x * 64 + jloc;
    float acc[16];
#pragma unroll
    for (int b = 0; b < 16; ++b) acc[b] = 0.f;
    const float* wp = w2 + (size_t)(ks * 128) * D2 + j;
#pragma unroll 2
    for (int k0 = 0; k0 < 128; k0 += 4) {
        float w0 = wp[0];
        float w1v = wp[D2];
        float w2v = wp[2 * (size_t)D2];
        float w3v = wp[3 * (size_t)D2];
        int kk = ks * 128 + k0;
#pragma unroll
        for (int b = 0; b < 16; ++b) {
            float4 mv = *(const float4*)&s_m1[b * 512 + kk];
            acc[b] += mv.x * w0 + mv.y * w1v + mv.z * w2v + mv.w * w3v;
        }
        wp += 4 * (size_t)D2;
    }
    float* pp = s_part + ks * 1088 + jloc * 17;
#pragma unroll
    for (int b = 0; b < 16; ++b) pp[b] = acc[b];
    __syncthreads();
    if (tid < 64) {
        int jj = blockIdx.x * 64 + tid;
        float sum[16];
#pragma unroll
        for (int b = 0; b < 16; ++b) sum[b] = 0.f;
#pragma unroll
        for (int s = 0; s < 4; ++s) {
            const float* q = s_part + s * 1088 + tid * 17;
#pragma unroll
            for (int b = 0; b < 16; ++b) sum[b] += q[b];
        }
        float bj = b2[jj], al = alpha2[jj], ga = g2[jj], be = bt2[jj], mu = mu2[jj];
        float iv = rsqrtf(var2[jj] + EPSV);
#pragma unroll
        for (int b = 0; b < 16; ++b) {
            float v = sum[b] + bj;
            v = v > 0.f ? v : al * v;
            m2[(size_t)b * D2 + jj] = ga * (v - mu) * iv + be;
        }
    }
}

// ---------------- Output head ----------------

__global__ void k_out(const float* __restrict__ m2, const float* __restrict__ h1,
                      const float* __restrict__ w_out, const float* __restrict__ b_out,
                      float* __restrict__ y) {
    __shared__ float sw[216];
    __shared__ float sb[3];
    int tid = threadIdx.x;
    if (tid < 216) sw[tid] = w_out[tid];
    if (tid < 3) sb[tid] = b_out[tid];
    __syncthreads();
    int t = blockIdx.x * 256 + tid;
    int n = t & (NN - 1);
    int b = t >> 12;
    float y0 = sb[0], y1 = sb[1], y2 = sb[2];
    const float4* gp = (const float4*)(m2 + (size_t)b * D2 + n * 8);
    float4 ga = gp[0], gb = gp[1];
    float gg[8] = {ga.x, ga.y, ga.z, ga.w, gb.x, gb.y, gb.z, gb.w};
#pragma unroll
    for (int g = 0; g < 8; ++g) {
        y0 += gg[g] * sw[g * 3 + 0];
        y1 += gg[g] * sw[g * 3 + 1];
        y2 += gg[g] * sw[g * 3 + 2];
    }
    const float* hp = h1 + n * 1024 + b * 64;
#pragma unroll
    for (int f = 0; f < 64; f += 4) {
        float4 hv = *(const float4*)(hp + f);
        y0 += hv.x * sw[(8 + f) * 3 + 0] + hv.y * sw[(9 + f) * 3 + 0] +
              hv.z * sw[(10 + f) * 3 + 0] + hv.w * sw[(11 + f) * 3 + 0];
        y1 += hv.x * sw[(8 + f) * 3 + 1] + hv.y * sw[(9 + f) * 3 + 1] +
              hv.z * sw[(10 + f) * 3 + 1] + hv.w * sw[(11 + f) * 3 + 1];
        y2 += hv.x * sw[(8 + f) * 3 + 2] + hv.y * sw[(9 + f) * 3 + 2] +
              hv.z * sw[(10 + f) * 3 + 2] + hv.w * sw[(11 + f) * 3 + 2];
    }
    float* yo = y + (size_t)b * (NN * 3) + n * 3;
    yo[0] = y0;
    yo[1] = y1;
    yo[2] = y2;
}

// ---------------- launcher ----------------

extern "C" void kernel_launch(void* const* d_in, const int* in_sizes, int n_in,
                              void* d_out, int out_size, void* d_ws, size_t ws_size,
                              hipStream_t stream) {
    const float* x      = (const float*)d_in[0];
    const float* pos    = (const float*)d_in[1];
    const float* hidden = (const float*)d_in[2];
    const int*   ei     = (const int*)d_in[3];
    const float* W0     = (const float*)d_in[4];
    const float* b0     = (const float*)d_in[5];
    const float* W1     = (const float*)d_in[6];
    const float* b1     = (const float*)d_in[7];
    const float* w_ih   = (const float*)d_in[8];
    const float* b_ih   = (const float*)d_in[9];
    const float* w_hh   = (const float*)d_in[10];
    const float* b_hh   = (const float*)d_in[11];
    const float* mlp_w1 = (const float*)d_in[12];
    const float* mlp_b1 = (const float*)d_in[13];
    const float* alpha1 = (const float*)d_in[14];
    const float* bn1g   = (const float*)d_in[15];
    const float* bn1b   = (const float*)d_in[16];
    const float* bn1m   = (const float*)d_in[17];
    const float* bn1v   = (const float*)d_in[18];
    const float* mlp_w2 = (const float*)d_in[19];
    const float* mlp_b2 = (const float*)d_in[20];
    const float* alpha2 = (const float*)d_in[21];
    const float* bn2g   = (const float*)d_in[22];
    const float* bn2b   = (const float*)d_in[23];
    const float* bn2m   = (const float*)d_in[24];
    const float* bn2v   = (const float*)d_in[25];
    const float* w_out  = (const float*)d_in[26];
    const float* b_out  = (const float*)d_in[27];

    float* out = (float*)d_out;
    float* ws = (float*)d_ws;

    float* bufA = ws;                 // 4096*1024: hws0, later reused as h1
    float* bufB = ws + 4194304;       // 4096*1024: hws1
    float* m2   = ws + 8388608;       // 16*32768
    float* nh   = ws + 8912896;       // 16*512
    float* m1s  = ws + 8921088;       // 16*512
    float* dis  = ws + 8929280;       // 4096
    int* wsi       = (int*)(ws + 8933376);
    int* cnt       = wsi;                       // 4096
    int* row_start = wsi + 4096;                // 4097
    int* cursor    = wsi + 4096 + 4097;         // 4096
    int* csr       = wsi + 4096 + 4097 + 4096;  // 65536

    const int* srcp = ei;
    const int* dstp = ei + EE;

    hipMemsetAsync(cnt, 0, 4096 * sizeof(int), stream);
    k_hist<<<EE / 256, 256, 0, stream>>>(dstp, cnt);
    k_scan<<<1, 1024, 0, stream>>>(cnt, row_start, cursor, dis);
    k_fill<<<EE / 256, 256, 0, stream>>>(srcp, dstp, cursor, csr);
    k_hw0<<<NN, 256, 0, stream>>>(pos, W0, dis, bufA);
    k_layer0<<<NN, 256, 0, stream>>>(bufA, row_start, csr, dis, b0, W1, bufB);
    k_agg1<<<NN, 256, 0, stream>>>(bufB, row_start, csr, dis, b1, bufA);
    k_gru<<<128, 256, 0, stream>>>(x, hidden, w_ih, b_ih, w_hh, b_hh, out + BB * NN * 3, nh);
    k_mlp1<<<128, 256, 0, stream>>>(nh, mlp_w1, mlp_b1, alpha1, bn1g, bn1b, bn1m, bn1v, m1s);
    k_mlp2<<<512, 256, 0, stream>>>(m1s, mlp_w2, mlp_b2, alpha2, bn2g, bn2b, bn2m, bn2v, m2);
    k_out<<<(BB * NN) / 256, 256, 0, stream>>>(m2, bufA, w_out, b_out, out);
}

// Round 3
// 175.291 us; speedup vs baseline: 1.9700x; 1.0129x over previous
//
#include <hip/hip_runtime.h>
#include <math.h>

#define BB 16
#define NN 4096
#define EE 65536
#define IN_F 128
#define HH 512
#define F1 64
#define D1 512
#define D2 32768
#define EPSV 1e-5f

// bf16 helpers (RNE pack, cheap unpack)
__device__ __forceinline__ unsigned bfpack2(float a, float b) {
    unsigned ua = __float_as_uint(a), ub = __float_as_uint(b);
    ua += 0x7fffu + ((ua >> 16) & 1u);
    ub += 0x7fffu + ((ub >> 16) & 1u);
    return (ua >> 16) | (ub & 0xffff0000u);
}
__device__ __forceinline__ float bflo(unsigned u) { return __uint_as_float(u << 16); }
__device__ __forceinline__ float bfhi(unsigned u) { return __uint_as_float(u & 0xffff0000u); }

// ---------------- GCN support: histogram / scan / CSR fill ----------------

__global__ void k_hist(const int* __restrict__ dst, int* __restrict__ cnt) {
    int i = blockIdx.x * 256 + threadIdx.x;
    if (i < EE) atomicAdd(&cnt[dst[i]], 1);
}

__global__ void k_scan(const int* __restrict__ cnt, int* __restrict__ row_start,
                       int* __restrict__ cursor, float* __restrict__ dis) {
    __shared__ int lds[1024];
    int tid = threadIdx.x;
    int v0 = cnt[tid * 4 + 0];
    int v1 = cnt[tid * 4 + 1];
    int v2 = cnt[tid * 4 + 2];
    int v3 = cnt[tid * 4 + 3];
    int s = v0 + v1 + v2 + v3;
    lds[tid] = s;
    __syncthreads();
    for (int off = 1; off < 1024; off <<= 1) {
        int t = (tid >= off) ? lds[tid - off] : 0;
        __syncthreads();
        lds[tid] += t;
        __syncthreads();
    }
    int e = (tid > 0) ? lds[tid - 1] : 0;
    int idx = tid * 4;
    row_start[idx + 0] = e; cursor[idx + 0] = e; dis[idx + 0] = rsqrtf((float)(v0 + 1)); e += v0;
    row_start[idx + 1] = e; cursor[idx + 1] = e; dis[idx + 1] = rsqrtf((float)(v1 + 1)); e += v1;
    row_start[idx + 2] = e; cursor[idx + 2] = e; dis[idx + 2] = rsqrtf((float)(v2 + 1)); e += v2;
    row_start[idx + 3] = e; cursor[idx + 3] = e; dis[idx + 3] = rsqrtf((float)(v3 + 1)); e += v3;
    if (tid == 1023) row_start[4096] = lds[1023];
}

__global__ void k_fill(const int* __restrict__ src, const int* __restrict__ dst,
                       int* __restrict__ cursor, int* __restrict__ csr_src) {
    int i = blockIdx.x * 256 + threadIdx.x;
    if (i < EE) {
        int d = dst[i];
        int p = atomicAdd(&cursor[d], 1);
        csr_src[p] = src[i];
    }
}

// ---------------- hws0 = bf16( dis[n] * (pos @ W0) ), layout [n][b][g] bf16 ----------------
// thread t: b = t>>4, g0 = (t&15)*4 -> one 8B (4xbf16) store

__global__ void k_hw0(const float* __restrict__ pos, const float* __restrict__ W0,
                      const float* __restrict__ dis, unsigned* __restrict__ hws0) {
    int n = blockIdx.x;
    int tid = threadIdx.x;
    int b = tid >> 4;
    int g0 = (tid & 15) * 4;
    float d = dis[n];
    const float* p = pos + b * (NN * 3) + n * 3;
    float p0 = p[0], p1 = p[1], p2 = p[2];
    float4 w0 = *(const float4*)(W0 + g0);
    float4 w1 = *(const float4*)(W0 + 64 + g0);
    float4 w2 = *(const float4*)(W0 + 128 + g0);
    float o0 = d * (p0 * w0.x + p1 * w1.x + p2 * w2.x);
    float o1 = d * (p0 * w0.y + p1 * w1.y + p2 * w2.y);
    float o2 = d * (p0 * w0.z + p1 * w1.z + p2 * w2.z);
    float o3 = d * (p0 * w0.w + p1 * w1.w + p2 * w2.w);
    uint2 pk;
    pk.x = bfpack2(o0, o1);
    pk.y = bfpack2(o2, o3);
    *(uint2*)(hws0 + (size_t)n * 512 + tid * 2) = pk;
}

// ---------------- layer0: aggregate hws0 (bf16 gather) + W1 matmul -> hws1 (bf16) ----------------

__global__ void k_layer0(const unsigned* __restrict__ hws0, const int* __restrict__ row_start,
                         const int* __restrict__ csr_src, const float* __restrict__ dis,
                         const float* __restrict__ bias0, const float* __restrict__ W1,
                         unsigned* __restrict__ hws1) {
    __shared__ float h0[16][72];
    int n = blockIdx.x;
    int tid = threadIdx.x;
    int b = tid >> 4;
    int g0 = (tid & 15) * 4;
    int rs = row_start[n], re = row_start[n + 1];
    float a0, a1, a2, a3;
    {
        uint2 v = *(const uint2*)(hws0 + (size_t)n * 512 + tid * 2);
        a0 = bflo(v.x); a1 = bfhi(v.x); a2 = bflo(v.y); a3 = bfhi(v.y);
    }
    int e = rs;
    for (; e + 1 < re; e += 2) {
        int s0 = csr_src[e], s1 = csr_src[e + 1];
        uint2 va = *(const uint2*)(hws0 + (size_t)s0 * 512 + tid * 2);
        uint2 vb = *(const uint2*)(hws0 + (size_t)s1 * 512 + tid * 2);
        a0 += bflo(va.x); a1 += bfhi(va.x); a2 += bflo(va.y); a3 += bfhi(va.y);
        a0 += bflo(vb.x); a1 += bfhi(vb.x); a2 += bflo(vb.y); a3 += bfhi(vb.y);
    }
    if (e < re) {
        int s0 = csr_src[e];
        uint2 va = *(const uint2*)(hws0 + (size_t)s0 * 512 + tid * 2);
        a0 += bflo(va.x); a1 += bfhi(va.x); a2 += bflo(va.y); a3 += bfhi(va.y);
    }
    float d = dis[n];
    float4 bg = *(const float4*)(bias0 + g0);
    *(float4*)&h0[b][g0] = make_float4(a0 * d + bg.x, a1 * d + bg.y, a2 * d + bg.z, a3 * d + bg.w);
    __syncthreads();
    float o0 = 0.f, o1 = 0.f, o2 = 0.f, o3 = 0.f;
#pragma unroll 8
    for (int f = 0; f < 64; ++f) {
        float hv = h0[b][f];
        float4 w = *(const float4*)(W1 + f * 64 + g0);
        o0 += hv * w.x; o1 += hv * w.y; o2 += hv * w.z; o3 += hv * w.w;
    }
    uint2 pk;
    pk.x = bfpack2(o0 * d, o1 * d);
    pk.y = bfpack2(o2 * d, o3 * d);
    *(uint2*)(hws1 + (size_t)n * 512 + tid * 2) = pk;
}

// ---------------- agg1: aggregate hws1 (bf16 gather) -> h1 (f32 [n][b][g]) ----------------

__global__ void k_agg1(const unsigned* __restrict__ hws1, const int* __restrict__ row_start,
                       const int* __restrict__ csr_src, const float* __restrict__ dis,
                       const float* __restrict__ bias1, float* __restrict__ h1) {
    int n = blockIdx.x;
    int tid = threadIdx.x;
    int g0 = (tid & 15) * 4;
    int rs = row_start[n], re = row_start[n + 1];
    float a0, a1, a2, a3;
    {
        uint2 v = *(const uint2*)(hws1 + (size_t)n * 512 + tid * 2);
        a0 = bflo(v.x); a1 = bfhi(v.x); a2 = bflo(v.y); a3 = bfhi(v.y);
    }
    int e = rs;
    for (; e + 1 < re; e += 2) {
        int s0 = csr_src[e], s1 = csr_src[e + 1];
        uint2 va = *(const uint2*)(hws1 + (size_t)s0 * 512 + tid * 2);
        uint2 vb = *(const uint2*)(hws1 + (size_t)s1 * 512 + tid * 2);
        a0 += bflo(va.x); a1 += bfhi(va.x); a2 += bflo(va.y); a3 += bfhi(va.y);
        a0 += bflo(vb.x); a1 += bfhi(vb.x); a2 += bflo(vb.y); a3 += bfhi(vb.y);
    }
    if (e < re) {
        int s0 = csr_src[e];
        uint2 va = *(const uint2*)(hws1 + (size_t)s0 * 512 + tid * 2);
        a0 += bflo(va.x); a1 += bfhi(va.x); a2 += bflo(va.y); a3 += bfhi(va.y);
    }
    float d = dis[n];
    float4 bg = *(const float4*)(bias1 + g0);
    *(float4*)(h1 + (size_t)n * 1024 + tid * 4) =
        make_float4(a0 * d + bg.x, a1 * d + bg.y, a2 * d + bg.z, a3 * d + bg.w);
}

// ---------------- GRUCell: 128 blocks = 16 b x 8 jblk ----------------

__global__ void k_gru(const float* __restrict__ x, const float* __restrict__ hidden,
                      const float* __restrict__ w_ih, const float* __restrict__ b_ih,
                      const float* __restrict__ w_hh, const float* __restrict__ b_hh,
                      float* __restrict__ nh_out, float* __restrict__ nh_ws) {
    __shared__ float s_x[128];
    __shared__ float s_h[512];
    __shared__ float s_p[4 * 64 * 7];
    int tid = threadIdx.x;
    int b = blockIdx.x >> 3;
    int jblk = blockIdx.x & 7;
    if (tid < 128) s_x[tid] = x[b * IN_F + tid];
    for (int i = tid; i < 512; i += 256) s_h[i] = hidden[b * HH + i];
    __syncthreads();
    int jloc = tid & 63;
    int ks = tid >> 6;  // 0..3
    int j = jblk * 64 + jloc;
    float air = 0.f, aiz = 0.f, ain = 0.f, ahr = 0.f, ahz = 0.f, ahn = 0.f;
    {
        const float4* wi0 = (const float4*)(w_ih + (size_t)j * IN_F + ks * 32);
        const float4* wi1 = (const float4*)(w_ih + (size_t)(HH + j) * IN_F + ks * 32);
        const float4* wi2 = (const float4*)(w_ih + (size_t)(2 * HH + j) * IN_F + ks * 32);
        const float4* xs = (const float4*)(s_x + ks * 32);
#pragma unroll
        for (int i = 0; i < 8; ++i) {
            float4 xv = xs[i];
            float4 a = wi0[i], c = wi1[i], d = wi2[i];
            air += xv.x * a.x + xv.y * a.y + xv.z * a.z + xv.w * a.w;
            aiz += xv.x * c.x + xv.y * c.y + xv.z * c.z + xv.w * c.w;
            ain += xv.x * d.x + xv.y * d.y + xv.z * d.z + xv.w * d.w;
        }
    }
    {
        const float4* wh0 = (const float4*)(w_hh + (size_t)j * HH + ks * 128);
        const float4* wh1 = (const float4*)(w_hh + (size_t)(HH + j) * HH + ks * 128);
        const float4* wh2 = (const float4*)(w_hh + (size_t)(2 * HH + j) * HH + ks * 128);
        const float4* hs = (const float4*)(s_h + ks * 128);
#pragma unroll 8
        for (int i = 0; i < 32; ++i) {
            float4 hv = hs[i];
            float4 a = wh0[i], c = wh1[i], d = wh2[i];
            ahr += hv.x * a.x + hv.y * a.y + hv.z * a.z + hv.w * a.w;
            ahz += hv.x * c.x + hv.y * c.y + hv.z * c.z + hv.w * c.w;
            ahn += hv.x * d.x + hv.y * d.y + hv.z * d.z + hv.w * d.w;
        }
    }
    float* pp = s_p + (ks * 64 + jloc) * 7;
    pp[0] = air; pp[1] = aiz; pp[2] = ain; pp[3] = ahr; pp[4] = ahz; pp[5] = ahn;
    __syncthreads();
    if (tid < 64) {
        int jj = jblk * 64 + tid;
        float v0 = 0.f, v1 = 0.f, v2 = 0.f, v3 = 0.f, v4 = 0.f, v5 = 0.f;
#pragma unroll
        for (int s = 0; s < 4; ++s) {
            const float* q = s_p + (s * 64 + tid) * 7;
            v0 += q[0]; v1 += q[1]; v2 += q[2]; v3 += q[3]; v4 += q[4]; v5 += q[5];
        }
        float ir = v0 + b_ih[jj], iz = v1 + b_ih[HH + jj], inn = v2 + b_ih[2 * HH + jj];
        float hr = v3 + b_hh[jj], hz = v4 + b_hh[HH + jj], hn = v5 + b_hh[2 * HH + jj];
        float r = 1.f / (1.f + expf(-(ir + hr)));
        float z = 1.f / (1.f + expf(-(iz + hz)));
        float nn = tanhf(inn + r * hn);
        float hprev = s_h[jj];
        float nh = (1.f - z) * nn + z * hprev;
        nh_out[b * HH + jj] = nh;
        nh_ws[b * HH + jj] = nh;
    }
}

// ---------------- MLP layer 1 ----------------

__global__ void k_mlp1(const float* __restrict__ nh, const float* __restrict__ w1,
                       const float* __restrict__ b1, const float* __restrict__ alpha1,
                       const float* __restrict__ g1, const float* __restrict__ bt1,
                       const float* __restrict__ mu1, const float* __restrict__ var1,
                       float* __restrict__ m1) {
    __shared__ float s_nh[512];
    __shared__ float s_p[4 * 64];
    int tid = threadIdx.x;
    int b = blockIdx.x >> 3;
    int jblk = blockIdx.x & 7;
    for (int i = tid; i < 512; i += 256) s_nh[i] = nh[b * HH + i];
    __syncthreads();
    int jloc = tid & 63;
    int ks = tid >> 6;
    int j = jblk * 64 + jloc;
    const float* wp = w1 + (size_t)(ks * 128) * D1 + j;
    float acc = 0.f;
#pragma unroll 4
    for (int k0 = 0; k0 < 128; k0 += 4) {
        float w0 = wp[0], w1v = wp[D1], w2v = wp[2 * D1], w3v = wp[3 * D1];
        float4 mv = *(const float4*)&s_nh[ks * 128 + k0];
        acc += mv.x * w0 + mv.y * w1v + mv.z * w2v + mv.w * w3v;
        wp += 4 * D1;
    }
    s_p[ks * 64 + jloc] = acc;
    __syncthreads();
    if (tid < 64) {
        int jj = jblk * 64 + tid;
        float v = s_p[tid] + s_p[64 + tid] + s_p[128 + tid] + s_p[192 + tid];
        v += b1[jj];
        float al = alpha1[jj];
        v = v > 0.f ? v : al * v;
        float iv = rsqrtf(var1[jj] + EPSV);
        m1[b * D1 + jj] = g1[jj] * (v - mu1[jj]) * iv + bt1[jj];
    }
}

// ---------------- MLP layer 2, split-K: 2048 blocks = 512 jtiles x 4 outer-k ----------------
// writes RAW partials (no bias/BN) part[(ok*16+b)*D2 + j]; reduce fused into k_out

__global__ void k_mlp2(const float* __restrict__ m1, const float* __restrict__ w2,
                       float* __restrict__ part) {
    __shared__ float s_part[4 * 64 * 17];
    int tid = threadIdx.x;
    int jt = blockIdx.x >> 2;
    int ok = blockIdx.x & 3;
    int jloc = tid & 63;
    int ks = tid >> 6;  // 0..3
    int j = jt * 64 + jloc;
    int kb = ok * 128 + ks * 32;
    float acc[16];
#pragma unroll
    for (int b = 0; b < 16; ++b) acc[b] = 0.f;
    const float* wp = w2 + (size_t)kb * D2 + j;
#pragma unroll 2
    for (int k0 = 0; k0 < 32; k0 += 4) {
        float w0 = wp[0];
        float w1v = wp[(size_t)D2];
        float w2v = wp[2 * (size_t)D2];
        float w3v = wp[3 * (size_t)D2];
#pragma unroll
        for (int b = 0; b < 16; ++b) {
            float4 mv = *(const float4*)(m1 + b * 512 + kb + k0);
            acc[b] += mv.x * w0 + mv.y * w1v + mv.z * w2v + mv.w * w3v;
        }
        wp += 4 * (size_t)D2;
    }
    float* pp = s_part + ks * 1088 + jloc * 17;
#pragma unroll
    for (int b = 0; b < 16; ++b) pp[b] = acc[b];
    __syncthreads();
    if (tid < 64) {
        int jj = jt * 64 + tid;
#pragma unroll
        for (int b = 0; b < 16; ++b) {
            float s = s_part[0 * 1088 + tid * 17 + b] + s_part[1 * 1088 + tid * 17 + b] +
                      s_part[2 * 1088 + tid * 17 + b] + s_part[3 * 1088 + tid * 17 + b];
            part[(size_t)(ok * 16 + b) * D2 + jj] = s;
        }
    }
}

// ---------------- Output head: fused mlp2-reduce + bias/PReLU/BN + [gru|h1] @ w_out ----------------

__global__ void k_out(const float* __restrict__ part, const float* __restrict__ h1,
                      const float* __restrict__ b2, const float* __restrict__ alpha2,
                      const float* __restrict__ g2, const float* __restrict__ bt2,
                      const float* __restrict__ mu2, const float* __restrict__ var2,
                      const float* __restrict__ w_out, const float* __restrict__ b_out,
                      float* __restrict__ y) {
    __shared__ float sw[216];
    __shared__ float sb[3];
    int tid = threadIdx.x;
    if (tid < 216) sw[tid] = w_out[tid];
    if (tid < 3) sb[tid] = b_out[tid];
    __syncthreads();
    int t = blockIdx.x * 256 + tid;
    int n = t & (NN - 1);
    int b = t >> 12;
    int j0 = n * 8;
    // reduce 4 k-partials
    float4 sA = make_float4(0.f, 0.f, 0.f, 0.f);
    float4 sB = make_float4(0.f, 0.f, 0.f, 0.f);
#pragma unroll
    for (int ok = 0; ok < 4; ++ok) {
        const float* pp = part + (size_t)(ok * 16 + b) * D2 + j0;
        float4 pa = *(const float4*)pp;
        float4 pb = *(const float4*)(pp + 4);
        sA.x += pa.x; sA.y += pa.y; sA.z += pa.z; sA.w += pa.w;
        sB.x += pb.x; sB.y += pb.y; sB.z += pb.z; sB.w += pb.w;
    }
    float raw[8] = {sA.x, sA.y, sA.z, sA.w, sB.x, sB.y, sB.z, sB.w};
    float4 bja = *(const float4*)(b2 + j0),    bjb = *(const float4*)(b2 + j0 + 4);
    float4 ala = *(const float4*)(alpha2 + j0), alb = *(const float4*)(alpha2 + j0 + 4);
    float4 gaa = *(const float4*)(g2 + j0),    gab = *(const float4*)(g2 + j0 + 4);
    float4 bea = *(const float4*)(bt2 + j0),   beb = *(const float4*)(bt2 + j0 + 4);
    float4 mua = *(const float4*)(mu2 + j0),   mub = *(const float4*)(mu2 + j0 + 4);
    float4 vaa = *(const float4*)(var2 + j0),  vab = *(const float4*)(var2 + j0 + 4);
    float bj[8] = {bja.x, bja.y, bja.z, bja.w, bjb.x, bjb.y, bjb.z, bjb.w};
    float al[8] = {ala.x, ala.y, ala.z, ala.w, alb.x, alb.y, alb.z, alb.w};
    float ga[8] = {gaa.x, gaa.y, gaa.z, gaa.w, gab.x, gab.y, gab.z, gab.w};
    float be[8] = {bea.x, bea.y, bea.z, bea.w, beb.x, beb.y, beb.z, beb.w};
    float mu[8] = {mua.x, mua.y, mua.z, mua.w, mub.x, mub.y, mub.z, mub.w};
    float va[8] = {vaa.x, vaa.y, vaa.z, vaa.w, vab.x, vab.y, vab.z, vab.w};
    float y0 = sb[0], y1 = sb[1], y2 = sb[2];
#pragma unroll
    for (int g = 0; g < 8; ++g) {
        float v = raw[g] + bj[g];
        v = v > 0.f ? v : al[g] * v;
        v = ga[g] * (v - mu[g]) * rsqrtf(va[g] + EPSV) + be[g];
        y0 += v * sw[g * 3 + 0];
        y1 += v * sw[g * 3 + 1];
        y2 += v * sw[g * 3 + 2];
    }
    const float* hp = h1 + (size_t)n * 1024 + b * 64;
#pragma unroll
    for (int f = 0; f < 64; f += 4) {
        float4 hv = *(const float4*)(hp + f);
        y0 += hv.x * sw[(8 + f) * 3 + 0] + hv.y * sw[(9 + f) * 3 + 0] +
              hv.z * sw[(10 + f) * 3 + 0] + hv.w * sw[(11 + f) * 3 + 0];
        y1 += hv.x * sw[(8 + f) * 3 + 1] + hv.y * sw[(9 + f) * 3 + 1] +
              hv.z * sw[(10 + f) * 3 + 1] + hv.w * sw[(11 + f) * 3 + 1];
        y2 += hv.x * sw[(8 + f) * 3 + 2] + hv.y * sw[(9 + f) * 3 + 2] +
              hv.z * sw[(10 + f) * 3 + 2] + hv.w * sw[(11 + f) * 3 + 2];
    }
    float* yo = y + (size_t)b * (NN * 3) + n * 3;
    yo[0] = y0;
    yo[1] = y1;
    yo[2] = y2;
}

// ---------------- launcher ----------------

extern "C" void kernel_launch(void* const* d_in, const int* in_sizes, int n_in,
                              void* d_out, int out_size, void* d_ws, size_t ws_size,
                              hipStream_t stream) {
    const float* x      = (const float*)d_in[0];
    const float* pos    = (const float*)d_in[1];
    const float* hidden = (const float*)d_in[2];
    const int*   ei     = (const int*)d_in[3];
    const float* W0     = (const float*)d_in[4];
    const float* b0     = (const float*)d_in[5];
    const float* W1     = (const float*)d_in[6];
    const float* b1     = (const float*)d_in[7];
    const float* w_ih   = (const float*)d_in[8];
    const float* b_ih   = (const float*)d_in[9];
    const float* w_hh   = (const float*)d_in[10];
    const float* b_hh   = (const float*)d_in[11];
    const float* mlp_w1 = (const float*)d_in[12];
    const float* mlp_b1 = (const float*)d_in[13];
    const float* alpha1 = (const float*)d_in[14];
    const float* bn1g   = (const float*)d_in[15];
    const float* bn1b   = (const float*)d_in[16];
    const float* bn1m   = (const float*)d_in[17];
    const float* bn1v   = (const float*)d_in[18];
    const float* mlp_w2 = (const float*)d_in[19];
    const float* mlp_b2 = (const float*)d_in[20];
    const float* alpha2 = (const float*)d_in[21];
    const float* bn2g   = (const float*)d_in[22];
    const float* bn2b   = (const float*)d_in[23];
    const float* bn2m   = (const float*)d_in[24];
    const float* bn2v   = (const float*)d_in[25];
    const float* w_out  = (const float*)d_in[26];
    const float* b_out  = (const float*)d_in[27];

    float* out = (float*)d_out;
    float* ws = (float*)d_ws;

    // workspace layout (float offsets)
    float* bufA = ws;                  // region 4M floats: hws0 (bf16, 8MB) then h1 (f32, 16MB)
    float* bufB = ws + 4194304;        // region 4M floats: hws1 (bf16, 4MB), then part (8MB)
    float* nh   = ws + 8388608;        // 16*512
    float* m1s  = ws + 8396800;        // 16*512
    float* dis  = ws + 8404992;        // 4096
    int* wsi       = (int*)(ws + 8409088);
    int* cnt       = wsi;                       // 4096
    int* row_start = wsi + 4096;                // 4097
    int* cursor    = wsi + 4096 + 4097;         // 4096
    int* csr       = wsi + 4096 + 4097 + 4096;  // 65536

    unsigned* hws0 = (unsigned*)bufA;
    unsigned* hws1 = (unsigned*)bufB;
    float* h1   = bufA;   // f32, written by k_agg1 after hws0 consumed
    float* part = bufB;   // f32 partials, written by k_mlp2 after hws1 consumed

    const int* srcp = ei;
    const int* dstp = ei + EE;

    hipMemsetAsync(cnt, 0, 4096 * sizeof(int), stream);
    k_hist<<<EE / 256, 256, 0, stream>>>(dstp, cnt);
    k_scan<<<1, 1024, 0, stream>>>(cnt, row_start, cursor, dis);
    k_fill<<<EE / 256, 256, 0, stream>>>(srcp, dstp, cursor, csr);
    k_hw0<<<NN, 256, 0, stream>>>(pos, W0, dis, hws0);
    k_layer0<<<NN, 256, 0, stream>>>(hws0, row_start, csr, dis, b0, W1, hws1);
    k_agg1<<<NN, 256, 0, stream>>>(hws1, row_start, csr, dis, b1, h1);
    k_gru<<<128, 256, 0, stream>>>(x, hidden, w_ih, b_ih, w_hh, b_hh, out + BB * NN * 3, nh);
    k_mlp1<<<128, 256, 0, stream>>>(nh, mlp_w1, mlp_b1, alpha1, bn1g, bn1b, bn1m, bn1v, m1s);
    k_mlp2<<<2048, 256, 0, stream>>>(m1s, mlp_w2, part);
    k_out<<<(BB * NN) / 256, 256, 0, stream>>>(part, h1, mlp_b2, alpha2, bn2g, bn2b, bn2m,
                                               bn2v, w_out, b_out, out);
}

// Round 4
// 150.797 us; speedup vs baseline: 2.2900x; 1.1624x over previous
//
#include <hip/hip_runtime.h>
#include <math.h>

#define BB 16
#define NN 4096
#define EE 65536
#define IN_F 128
#define HH 512
#define F1 64
#define D1 512
#define D2 32768
#define EPSV 1e-5f

// bf16 helpers (RNE pack, cheap unpack)
__device__ __forceinline__ unsigned bfpack2(float a, float b) {
    unsigned ua = __float_as_uint(a), ub = __float_as_uint(b);
    ua += 0x7fffu + ((ua >> 16) & 1u);
    ub += 0x7fffu + ((ub >> 16) & 1u);
    return (ua >> 16) | (ub & 0xffff0000u);
}
__device__ __forceinline__ float bflo(unsigned u) { return __uint_as_float(u << 16); }
__device__ __forceinline__ float bfhi(unsigned u) { return __uint_as_float(u & 0xffff0000u); }

// ---------------- GCN support: histogram / scan / CSR fill ----------------

__global__ void k_hist(const int* __restrict__ dst, int* __restrict__ cnt) {
    int i = blockIdx.x * 256 + threadIdx.x;
    if (i < EE) atomicAdd(&cnt[dst[i]], 1);
}

__global__ void k_scan(const int* __restrict__ cnt, int* __restrict__ row_start,
                       int* __restrict__ cursor, float* __restrict__ dis) {
    __shared__ int lds[1024];
    int tid = threadIdx.x;
    int v0 = cnt[tid * 4 + 0];
    int v1 = cnt[tid * 4 + 1];
    int v2 = cnt[tid * 4 + 2];
    int v3 = cnt[tid * 4 + 3];
    int s = v0 + v1 + v2 + v3;
    lds[tid] = s;
    __syncthreads();
    for (int off = 1; off < 1024; off <<= 1) {
        int t = (tid >= off) ? lds[tid - off] : 0;
        __syncthreads();
        lds[tid] += t;
        __syncthreads();
    }
    int e = (tid > 0) ? lds[tid - 1] : 0;
    int idx = tid * 4;
    row_start[idx + 0] = e; cursor[idx + 0] = e; dis[idx + 0] = rsqrtf((float)(v0 + 1)); e += v0;
    row_start[idx + 1] = e; cursor[idx + 1] = e; dis[idx + 1] = rsqrtf((float)(v1 + 1)); e += v1;
    row_start[idx + 2] = e; cursor[idx + 2] = e; dis[idx + 2] = rsqrtf((float)(v2 + 1)); e += v2;
    row_start[idx + 3] = e; cursor[idx + 3] = e; dis[idx + 3] = rsqrtf((float)(v3 + 1)); e += v3;
    if (tid == 1023) row_start[4096] = lds[1023];
}

__global__ void k_fill(const int* __restrict__ src, const int* __restrict__ dst,
                       int* __restrict__ cursor, int* __restrict__ csr_src) {
    int i = blockIdx.x * 256 + threadIdx.x;
    if (i < EE) {
        int d = dst[i];
        int p = atomicAdd(&cursor[d], 1);
        csr_src[p] = src[i];
    }
}

// ---------------- hws0 = bf16( dis[n] * (pos @ W0) ), layout [n][b][g] bf16 ----------------

__global__ void k_hw0(const float* __restrict__ pos, const float* __restrict__ W0,
                      const float* __restrict__ dis, unsigned* __restrict__ hws0) {
    int n = blockIdx.x;
    int tid = threadIdx.x;
    int b = tid >> 4;
    int g0 = (tid & 15) * 4;
    float d = dis[n];
    const float* p = pos + b * (NN * 3) + n * 3;
    float p0 = p[0], p1 = p[1], p2 = p[2];
    float4 w0 = *(const float4*)(W0 + g0);
    float4 w1 = *(const float4*)(W0 + 64 + g0);
    float4 w2 = *(const float4*)(W0 + 128 + g0);
    float o0 = d * (p0 * w0.x + p1 * w1.x + p2 * w2.x);
    float o1 = d * (p0 * w0.y + p1 * w1.y + p2 * w2.y);
    float o2 = d * (p0 * w0.z + p1 * w1.z + p2 * w2.z);
    float o3 = d * (p0 * w0.w + p1 * w1.w + p2 * w2.w);
    uint2 pk;
    pk.x = bfpack2(o0, o1);
    pk.y = bfpack2(o2, o3);
    *(uint2*)(hws0 + (size_t)n * 512 + tid * 2) = pk;
}

// ---------------- layer0: aggregate hws0 (bf16 gather) + W1 matmul -> hws1 (bf16) ----------------

__global__ void k_layer0(const unsigned* __restrict__ hws0, const int* __restrict__ row_start,
                         const int* __restrict__ csr_src, const float* __restrict__ dis,
                         const float* __restrict__ bias0, const float* __restrict__ W1,
                         unsigned* __restrict__ hws1) {
    __shared__ float h0[16][72];
    int n = blockIdx.x;
    int tid = threadIdx.x;
    int b = tid >> 4;
    int g0 = (tid & 15) * 4;
    int rs = row_start[n], re = row_start[n + 1];
    float a0, a1, a2, a3;
    {
        uint2 v = *(const uint2*)(hws0 + (size_t)n * 512 + tid * 2);
        a0 = bflo(v.x); a1 = bfhi(v.x); a2 = bflo(v.y); a3 = bfhi(v.y);
    }
    int e = rs;
    for (; e + 1 < re; e += 2) {
        int s0 = csr_src[e], s1 = csr_src[e + 1];
        uint2 va = *(const uint2*)(hws0 + (size_t)s0 * 512 + tid * 2);
        uint2 vb = *(const uint2*)(hws0 + (size_t)s1 * 512 + tid * 2);
        a0 += bflo(va.x); a1 += bfhi(va.x); a2 += bflo(va.y); a3 += bfhi(va.y);
        a0 += bflo(vb.x); a1 += bfhi(vb.x); a2 += bflo(vb.y); a3 += bfhi(vb.y);
    }
    if (e < re) {
        int s0 = csr_src[e];
        uint2 va = *(const uint2*)(hws0 + (size_t)s0 * 512 + tid * 2);
        a0 += bflo(va.x); a1 += bfhi(va.x); a2 += bflo(va.y); a3 += bfhi(va.y);
    }
    float d = dis[n];
    float4 bg = *(const float4*)(bias0 + g0);
    *(float4*)&h0[b][g0] = make_float4(a0 * d + bg.x, a1 * d + bg.y, a2 * d + bg.z, a3 * d + bg.w);
    __syncthreads();
    float o0 = 0.f, o1 = 0.f, o2 = 0.f, o3 = 0.f;
#pragma unroll 8
    for (int f = 0; f < 64; ++f) {
        float hv = h0[b][f];
        float4 w = *(const float4*)(W1 + f * 64 + g0);
        o0 += hv * w.x; o1 += hv * w.y; o2 += hv * w.z; o3 += hv * w.w;
    }
    uint2 pk;
    pk.x = bfpack2(o0 * d, o1 * d);
    pk.y = bfpack2(o2 * d, o3 * d);
    *(uint2*)(hws1 + (size_t)n * 512 + tid * 2) = pk;
}

// ---------------- agg1: aggregate hws1 (bf16 gather) -> h1 (f32 [n][b][g]) ----------------

__global__ void k_agg1(const unsigned* __restrict__ hws1, const int* __restrict__ row_start,
                       const int* __restrict__ csr_src, const float* __restrict__ dis,
                       const float* __restrict__ bias1, float* __restrict__ h1) {
    int n = blockIdx.x;
    int tid = threadIdx.x;
    int g0 = (tid & 15) * 4;
    int rs = row_start[n], re = row_start[n + 1];
    float a0, a1, a2, a3;
    {
        uint2 v = *(const uint2*)(hws1 + (size_t)n * 512 + tid * 2);
        a0 = bflo(v.x); a1 = bfhi(v.x); a2 = bflo(v.y); a3 = bfhi(v.y);
    }
    int e = rs;
    for (; e + 1 < re; e += 2) {
        int s0 = csr_src[e], s1 = csr_src[e + 1];
        uint2 va = *(const uint2*)(hws1 + (size_t)s0 * 512 + tid * 2);
        uint2 vb = *(const uint2*)(hws1 + (size_t)s1 * 512 + tid * 2);
        a0 += bflo(va.x); a1 += bfhi(va.x); a2 += bflo(va.y); a3 += bfhi(va.y);
        a0 += bflo(vb.x); a1 += bfhi(vb.x); a2 += bflo(vb.y); a3 += bfhi(vb.y);
    }
    if (e < re) {
        int s0 = csr_src[e];
        uint2 va = *(const uint2*)(hws1 + (size_t)s0 * 512 + tid * 2);
        a0 += bflo(va.x); a1 += bfhi(va.x); a2 += bflo(va.y); a3 += bfhi(va.y);
    }
    float d = dis[n];
    float4 bg = *(const float4*)(bias1 + g0);
    *(float4*)(h1 + (size_t)n * 1024 + tid * 4) =
        make_float4(a0 * d + bg.x, a1 * d + bg.y, a2 * d + bg.z, a3 * d + bg.w);
}

// ---------------- GRUCell: 128 blocks = 16 b x 8 jblk ----------------

__global__ void k_gru(const float* __restrict__ x, const float* __restrict__ hidden,
                      const float* __restrict__ w_ih, const float* __restrict__ b_ih,
                      const float* __restrict__ w_hh, const float* __restrict__ b_hh,
                      float* __restrict__ nh_out, float* __restrict__ nh_ws) {
    __shared__ float s_x[128];
    __shared__ float s_h[512];
    __shared__ float s_p[4 * 64 * 7];
    int tid = threadIdx.x;
    int b = blockIdx.x >> 3;
    int jblk = blockIdx.x & 7;
    if (tid < 128) s_x[tid] = x[b * IN_F + tid];
    for (int i = tid; i < 512; i += 256) s_h[i] = hidden[b * HH + i];
    __syncthreads();
    int jloc = tid & 63;
    int ks = tid >> 6;  // 0..3
    int j = jblk * 64 + jloc;
    float air = 0.f, aiz = 0.f, ain = 0.f, ahr = 0.f, ahz = 0.f, ahn = 0.f;
    {
        const float4* wi0 = (const float4*)(w_ih + (size_t)j * IN_F + ks * 32);
        const float4* wi1 = (const float4*)(w_ih + (size_t)(HH + j) * IN_F + ks * 32);
        const float4* wi2 = (const float4*)(w_ih + (size_t)(2 * HH + j) * IN_F + ks * 32);
        const float4* xs = (const float4*)(s_x + ks * 32);
#pragma unroll
        for (int i = 0; i < 8; ++i) {
            float4 xv = xs[i];
            float4 a = wi0[i], c = wi1[i], d = wi2[i];
            air += xv.x * a.x + xv.y * a.y + xv.z * a.z + xv.w * a.w;
            aiz += xv.x * c.x + xv.y * c.y + xv.z * c.z + xv.w * c.w;
            ain += xv.x * d.x + xv.y * d.y + xv.z * d.z + xv.w * d.w;
        }
    }
    {
        const float4* wh0 = (const float4*)(w_hh + (size_t)j * HH + ks * 128);
        const float4* wh1 = (const float4*)(w_hh + (size_t)(HH + j) * HH + ks * 128);
        const float4* wh2 = (const float4*)(w_hh + (size_t)(2 * HH + j) * HH + ks * 128);
        const float4* hs = (const float4*)(s_h + ks * 128);
#pragma unroll 8
        for (int i = 0; i < 32; ++i) {
            float4 hv = hs[i];
            float4 a = wh0[i], c = wh1[i], d = wh2[i];
            ahr += hv.x * a.x + hv.y * a.y + hv.z * a.z + hv.w * a.w;
            ahz += hv.x * c.x + hv.y * c.y + hv.z * c.z + hv.w * c.w;
            ahn += hv.x * d.x + hv.y * d.y + hv.z * d.z + hv.w * d.w;
        }
    }
    float* pp = s_p + (ks * 64 + jloc) * 7;
    pp[0] = air; pp[1] = aiz; pp[2] = ain; pp[3] = ahr; pp[4] = ahz; pp[5] = ahn;
    __syncthreads();
    if (tid < 64) {
        int jj = jblk * 64 + tid;
        float v0 = 0.f, v1 = 0.f, v2 = 0.f, v3 = 0.f, v4 = 0.f, v5 = 0.f;
#pragma unroll
        for (int s = 0; s < 4; ++s) {
            const float* q = s_p + (s * 64 + tid) * 7;
            v0 += q[0]; v1 += q[1]; v2 += q[2]; v3 += q[3]; v4 += q[4]; v5 += q[5];
        }
        float ir = v0 + b_ih[jj], iz = v1 + b_ih[HH + jj], inn = v2 + b_ih[2 * HH + jj];
        float hr = v3 + b_hh[jj], hz = v4 + b_hh[HH + jj], hn = v5 + b_hh[2 * HH + jj];
        float r = 1.f / (1.f + expf(-(ir + hr)));
        float z = 1.f / (1.f + expf(-(iz + hz)));
        float nn = tanhf(inn + r * hn);
        float hprev = s_h[jj];
        float nh = (1.f - z) * nn + z * hprev;
        nh_out[b * HH + jj] = nh;
        nh_ws[b * HH + jj] = nh;
    }
}

// ---------------- MLP layer 1 ----------------

__global__ void k_mlp1(const float* __restrict__ nh, const float* __restrict__ w1,
                       const float* __restrict__ b1, const float* __restrict__ alpha1,
                       const float* __restrict__ g1, const float* __restrict__ bt1,
                       const float* __restrict__ mu1, const float* __restrict__ var1,
                       float* __restrict__ m1) {
    __shared__ float s_nh[512];
    __shared__ float s_p[4 * 64];
    int tid = threadIdx.x;
    int b = blockIdx.x >> 3;
    int jblk = blockIdx.x & 7;
    for (int i = tid; i < 512; i += 256) s_nh[i] = nh[b * HH + i];
    __syncthreads();
    int jloc = tid & 63;
    int ks = tid >> 6;
    int j = jblk * 64 + jloc;
    const float* wp = w1 + (size_t)(ks * 128) * D1 + j;
    float acc = 0.f;
#pragma unroll 4
    for (int k0 = 0; k0 < 128; k0 += 4) {
        float w0 = wp[0], w1v = wp[D1], w2v = wp[2 * D1], w3v = wp[3 * D1];
        float4 mv = *(const float4*)&s_nh[ks * 128 + k0];
        acc += mv.x * w0 + mv.y * w1v + mv.z * w2v + mv.w * w3v;
        wp += 4 * D1;
    }
    s_p[ks * 64 + jloc] = acc;
    __syncthreads();
    if (tid < 64) {
        int jj = jblk * 64 + tid;
        float v = s_p[tid] + s_p[64 + tid] + s_p[128 + tid] + s_p[192 + tid];
        v += b1[jj];
        float al = alpha1[jj];
        v = v > 0.f ? v : al * v;
        float iv = rsqrtf(var1[jj] + EPSV);
        m1[b * D1 + jj] = g1[jj] * (v - mu1[jj]) * iv + bt1[jj];
    }
}

// ---------------- MLP layer 2: 512 blocks = 64 jt (512 cols) x 8 ok (64 k) ----------------
// thread owns 2 j cols x 16 b; m1 slice in LDS; 4-deep w2 register prefetch.
// writes RAW partials part[(ok*16+b)*D2 + j]; reduce+BN fused into k_out

__global__ void k_mlp2(const float* __restrict__ m1, const float* __restrict__ w2,
                       float* __restrict__ part) {
    __shared__ float s_m1[16 * 64];
    int tid = threadIdx.x;
    int jt = blockIdx.x >> 3;
    int ok = blockIdx.x & 7;
    // stage m1[16][64] slice: thread loads one float4
    {
        int b = tid >> 4, kg = tid & 15;
        *(float4*)&s_m1[b * 64 + kg * 4] = *(const float4*)(m1 + b * 512 + ok * 64 + kg * 4);
    }
    __syncthreads();
    int j = jt * 512 + tid * 2;
    const float* wp = w2 + (size_t)(ok * 64) * D2 + j;
    float2 wb0 = *(const float2*)(wp + 0 * (size_t)D2);
    float2 wb1 = *(const float2*)(wp + 1 * (size_t)D2);
    float2 wb2 = *(const float2*)(wp + 2 * (size_t)D2);
    float2 wb3 = *(const float2*)(wp + 3 * (size_t)D2);
    float acc0[16], acc1[16];
#pragma unroll
    for (int b = 0; b < 16; ++b) { acc0[b] = 0.f; acc1[b] = 0.f; }
    for (int k4 = 0; k4 < 64; k4 += 4) {
        float2 c0 = wb0, c1 = wb1, c2 = wb2, c3 = wb3;
        int kp = (k4 + 4 < 64) ? k4 + 4 : 0;  // clamp: last prefetch unused
        wb0 = *(const float2*)(wp + (size_t)(kp + 0) * D2);
        wb1 = *(const float2*)(wp + (size_t)(kp + 1) * D2);
        wb2 = *(const float2*)(wp + (size_t)(kp + 2) * D2);
        wb3 = *(const float2*)(wp + (size_t)(kp + 3) * D2);
#pragma unroll
        for (int b = 0; b < 16; ++b) {
            float2 p01 = *(const float2*)&s_m1[b * 64 + k4];
            float2 p23 = *(const float2*)&s_m1[b * 64 + k4 + 2];
            acc0[b] += p01.x * c0.x + p01.y * c1.x + p23.x * c2.x + p23.y * c3.x;
            acc1[b] += p01.x * c0.y + p01.y * c1.y + p23.x * c2.y + p23.y * c3.y;
        }
    }
    float* pb = part + (size_t)(ok * 16) * D2 + j;
#pragma unroll
    for (int b = 0; b < 16; ++b) {
        *(float2*)(pb + (size_t)b * D2) = make_float2(acc0[b], acc1[b]);
    }
}

// ---------------- Output head: fused 8-way mlp2-reduce + bias/PReLU/BN + [gru|h1] @ w_out ----------------

__global__ void k_out(const float* __restrict__ part, const float* __restrict__ h1,
                      const float* __restrict__ b2, const float* __restrict__ alpha2,
                      const float* __restrict__ g2, const float* __restrict__ bt2,
                      const float* __restrict__ mu2, const float* __restrict__ var2,
                      const float* __restrict__ w_out, const float* __restrict__ b_out,
                      float* __restrict__ y) {
    __shared__ float sw[216];
    __shared__ float sb[3];
    int tid = threadIdx.x;
    if (tid < 216) sw[tid] = w_out[tid];
    if (tid < 3) sb[tid] = b_out[tid];
    __syncthreads();
    int t = blockIdx.x * 256 + tid;
    int n = t & (NN - 1);
    int b = t >> 12;
    int j0 = n * 8;
    float4 sA = make_float4(0.f, 0.f, 0.f, 0.f);
    float4 sB = make_float4(0.f, 0.f, 0.f, 0.f);
#pragma unroll
    for (int ok = 0; ok < 8; ++ok) {
        const float* pp = part + (size_t)(ok * 16 + b) * D2 + j0;
        float4 pa = *(const float4*)pp;
        float4 pb = *(const float4*)(pp + 4);
        sA.x += pa.x; sA.y += pa.y; sA.z += pa.z; sA.w += pa.w;
        sB.x += pb.x; sB.y += pb.y; sB.z += pb.z; sB.w += pb.w;
    }
    float raw[8] = {sA.x, sA.y, sA.z, sA.w, sB.x, sB.y, sB.z, sB.w};
    float4 bja = *(const float4*)(b2 + j0),    bjb = *(const float4*)(b2 + j0 + 4);
    float4 ala = *(const float4*)(alpha2 + j0), alb = *(const float4*)(alpha2 + j0 + 4);
    float4 gaa = *(const float4*)(g2 + j0),    gab = *(const float4*)(g2 + j0 + 4);
    float4 bea = *(const float4*)(bt2 + j0),   beb = *(const float4*)(bt2 + j0 + 4);
    float4 mua = *(const float4*)(mu2 + j0),   mub = *(const float4*)(mu2 + j0 + 4);
    float4 vaa = *(const float4*)(var2 + j0),  vab = *(const float4*)(var2 + j0 + 4);
    float bj[8] = {bja.x, bja.y, bja.z, bja.w, bjb.x, bjb.y, bjb.z, bjb.w};
    float al[8] = {ala.x, ala.y, ala.z, ala.w, alb.x, alb.y, alb.z, alb.w};
    float ga[8] = {gaa.x, gaa.y, gaa.z, gaa.w, gab.x, gab.y, gab.z, gab.w};
    float be[8] = {bea.x, bea.y, bea.z, bea.w, beb.x, beb.y, beb.z, beb.w};
    float mu[8] = {mua.x, mua.y, mua.z, mua.w, mub.x, mub.y, mub.z, mub.w};
    float va[8] = {vaa.x, vaa.y, vaa.z, vaa.w, vab.x, vab.y, vab.z, vab.w};
    float y0 = sb[0], y1 = sb[1], y2 = sb[2];
#pragma unroll
    for (int g = 0; g < 8; ++g) {
        float v = raw[g] + bj[g];
        v = v > 0.f ? v : al[g] * v;
        v = ga[g] * (v - mu[g]) * rsqrtf(va[g] + EPSV) + be[g];
        y0 += v * sw[g * 3 + 0];
        y1 += v * sw[g * 3 + 1];
        y2 += v * sw[g * 3 + 2];
    }
    const float* hp = h1 + (size_t)n * 1024 + b * 64;
#pragma unroll
    for (int f = 0; f < 64; f += 4) {
        float4 hv = *(const float4*)(hp + f);
        y0 += hv.x * sw[(8 + f) * 3 + 0] + hv.y * sw[(9 + f) * 3 + 0] +
              hv.z * sw[(10 + f) * 3 + 0] + hv.w * sw[(11 + f) * 3 + 0];
        y1 += hv.x * sw[(8 + f) * 3 + 1] + hv.y * sw[(9 + f) * 3 + 1] +
              hv.z * sw[(10 + f) * 3 + 1] + hv.w * sw[(11 + f) * 3 + 1];
        y2 += hv.x * sw[(8 + f) * 3 + 2] + hv.y * sw[(9 + f) * 3 + 2] +
              hv.z * sw[(10 + f) * 3 + 2] + hv.w * sw[(11 + f) * 3 + 2];
    }
    float* yo = y + (size_t)b * (NN * 3) + n * 3;
    yo[0] = y0;
    yo[1] = y1;
    yo[2] = y2;
}

// ---------------- launcher ----------------

extern "C" void kernel_launch(void* const* d_in, const int* in_sizes, int n_in,
                              void* d_out, int out_size, void* d_ws, size_t ws_size,
                              hipStream_t stream) {
    const float* x      = (const float*)d_in[0];
    const float* pos    = (const float*)d_in[1];
    const float* hidden = (const float*)d_in[2];
    const int*   ei     = (const int*)d_in[3];
    const float* W0     = (const float*)d_in[4];
    const float* b0     = (const float*)d_in[5];
    const float* W1     = (const float*)d_in[6];
    const float* b1     = (const float*)d_in[7];
    const float* w_ih   = (const float*)d_in[8];
    const float* b_ih   = (const float*)d_in[9];
    const float* w_hh   = (const float*)d_in[10];
    const float* b_hh   = (const float*)d_in[11];
    const float* mlp_w1 = (const float*)d_in[12];
    const float* mlp_b1 = (const float*)d_in[13];
    const float* alpha1 = (const float*)d_in[14];
    const float* bn1g   = (const float*)d_in[15];
    const float* bn1b   = (const float*)d_in[16];
    const float* bn1m   = (const float*)d_in[17];
    const float* bn1v   = (const float*)d_in[18];
    const float* mlp_w2 = (const float*)d_in[19];
    const float* mlp_b2 = (const float*)d_in[20];
    const float* alpha2 = (const float*)d_in[21];
    const float* bn2g   = (const float*)d_in[22];
    const float* bn2b   = (const float*)d_in[23];
    const float* bn2m   = (const float*)d_in[24];
    const float* bn2v   = (const float*)d_in[25];
    const float* w_out  = (const float*)d_in[26];
    const float* b_out  = (const float*)d_in[27];

    float* out = (float*)d_out;
    float* ws = (float*)d_ws;

    // workspace layout (float offsets)
    float* bufA = ws;                  // 4M floats: hws0 (bf16 8MB) then h1 (f32 16MB)
    float* bufB = ws + 4194304;        // 4M floats: hws1 (bf16 8MB), then part (f32 16MB)
    float* nh   = ws + 8388608;        // 16*512
    float* m1s  = ws + 8396800;        // 16*512
    float* dis  = ws + 8404992;        // 4096
    int* wsi       = (int*)(ws + 8409088);
    int* cnt       = wsi;                       // 4096
    int* row_start = wsi + 4096;                // 4097
    int* cursor    = wsi + 4096 + 4097;         // 4096
    int* csr       = wsi + 4096 + 4097 + 4096;  // 65536

    unsigned* hws0 = (unsigned*)bufA;
    unsigned* hws1 = (unsigned*)bufB;
    float* h1   = bufA;   // f32, written by k_agg1 after hws0 consumed
    float* part = bufB;   // f32 partials (8*16 x D2), written after hws1 consumed

    const int* srcp = ei;
    const int* dstp = ei + EE;

    hipMemsetAsync(cnt, 0, 4096 * sizeof(int), stream);
    k_hist<<<EE / 256, 256, 0, stream>>>(dstp, cnt);
    k_scan<<<1, 1024, 0, stream>>>(cnt, row_start, cursor, dis);
    k_fill<<<EE / 256, 256, 0, stream>>>(srcp, dstp, cursor, csr);
    k_hw0<<<NN, 256, 0, stream>>>(pos, W0, dis, hws0);
    k_layer0<<<NN, 256, 0, stream>>>(hws0, row_start, csr, dis, b0, W1, hws1);
    k_agg1<<<NN, 256, 0, stream>>>(hws1, row_start, csr, dis, b1, h1);
    k_gru<<<128, 256, 0, stream>>>(x, hidden, w_ih, b_ih, w_hh, b_hh, out + BB * NN * 3, nh);
    k_mlp1<<<128, 256, 0, stream>>>(nh, mlp_w1, mlp_b1, alpha1, bn1g, bn1b, bn1m, bn1v, m1s);
    k_mlp2<<<512, 256, 0, stream>>>(m1s, mlp_w2, part);
    k_out<<<(BB * NN) / 256, 256, 0, stream>>>(part, h1, mlp_b2, alpha2, bn2g, bn2b, bn2m,
                                               bn2v, w_out, b_out, out);
}